// Round 4
// baseline (340.990 us; speedup 1.0000x reference)
//
#include <hip/hip_runtime.h>

#define NB   4
#define SEQ  4096
#define EMB  1024
#define HS   64

typedef __attribute__((ext_vector_type(8))) short bf16x8;   // 8 bf16 = 4 VGPRs
typedef __attribute__((ext_vector_type(4))) float f32x4;    // MFMA C/D

__device__ inline unsigned short f2bf(float f) {  // fp32 -> bf16 RNE
  unsigned int u = __float_as_uint(f);
  u += 0x7fffu + ((u >> 16) & 1u);
  return (unsigned short)(u >> 16);
}
__device__ inline float bf2f(unsigned short h) {
  return __uint_as_float(((unsigned int)h) << 16);
}
// ushort index of 16B chunk (row, c) in a 64x64 bf16 LDS tile, XOR-swizzled
// so b128 frag reads (16 lanes = 16 consecutive rows, same c) are conflict-free.
__device__ inline int swzi(int row, int c) {
  return row * 64 + ((c ^ (row & 7)) << 3);
}

// ---------------------------------------------------------------------------
// W prep: split Wq*scale*log2e | Wk | Wv into bf16 hi/lo [192][1024].
// Rows 0..63 = Wq (pre-scaled), 64..127 = Wk, 128..191 = Wv.
// ---------------------------------------------------------------------------
__global__ __launch_bounds__(256) void wprep(
    const float* __restrict__ Wk, const float* __restrict__ Wq,
    const float* __restrict__ Wv,
    unsigned short* __restrict__ Wh, unsigned short* __restrict__ Wl) {
  int i = blockIdx.x * 256 + threadIdx.x;  // float4 id, 192*1024/4 = 49152
  int e = i >> 8;   // row 0..191
  int c = i & 255;  // float4 col
  float4 v;
  float sc = 1.0f;
  if (e < 64)       { v = ((const float4*)Wq)[e * 256 + c];
                      sc = 0.18033688011112042f; }  // (1/sqrt(64))*log2(e)
  else if (e < 128)   v = ((const float4*)Wk)[(e - 64) * 256 + c];
  else                v = ((const float4*)Wv)[(e - 128) * 256 + c];
  v.x *= sc; v.y *= sc; v.z *= sc; v.w *= sc;
  ushort4 hv, lv;
  hv.x = f2bf(v.x); lv.x = f2bf(v.x - bf2f(hv.x));
  hv.y = f2bf(v.y); lv.y = f2bf(v.y - bf2f(hv.y));
  hv.z = f2bf(v.z); lv.z = f2bf(v.z - bf2f(hv.z));
  hv.w = f2bf(v.w); lv.w = f2bf(v.w - bf2f(hv.w));
  *(ushort4*)&Wh[i * 4] = hv;
  *(ushort4*)&Wl[i * 4] = lv;
}

// ---------------------------------------------------------------------------
// QKV projection on MFMA, split-bf16 (x hi/lo in-flight, W hi/lo precomputed):
// C = x . W^T per gy in {q,k,v}. Grid (256, 3), 256 thr = 4 waves.
// BM=64, BN=64, BK=64. Wave owns a 32x32 quadrant (2x2 16x16 C-tiles).
// acc += Ah.Bh + Ah.Bl + Al.Bh  (xl.wl term ~2^-18, dropped).
// Outputs: qh/ql, kh/kl bf16 hi/lo [B][N][H]; vt bf16 [B][H][N].
// ---------------------------------------------------------------------------
__global__ __launch_bounds__(256) void qkv_mfma(
    const float* __restrict__ x,
    const unsigned short* __restrict__ Wh, const unsigned short* __restrict__ Wl,
    unsigned short* __restrict__ qh, unsigned short* __restrict__ ql,
    unsigned short* __restrict__ kh, unsigned short* __restrict__ kl,
    unsigned short* __restrict__ vt) {
  __shared__ __align__(16) unsigned short XhS[4096];
  __shared__ __align__(16) unsigned short XlS[4096];
  __shared__ __align__(16) unsigned short WhS[4096];
  __shared__ __align__(16) unsigned short WlS[4096];

  const int t  = threadIdx.x;
  const int l  = t & 63;
  const int li = l & 15;
  const int g  = l >> 4;
  const int w  = t >> 6;
  const int m0 = blockIdx.x * 64;
  const int b  = m0 >> 12;
  const int n0 = m0 & 4095;
  const int gy = blockIdx.y;  // 0=q, 1=k, 2=v

  // --- staging maps ---
  // x: thread -> 16 consecutive floats of one row
  const int xr  = t >> 2;            // row 0..63
  const int xc2 = (t & 3) * 2;       // first 16B-chunk id (of its 2)
  const float* xp = x + (m0 + xr) * EMB + (t & 3) * 16;
  // W: thread -> 2 16B chunks
  const int wr0 = t >> 3,        wcc0 = t & 7;
  const int wr1 = (t + 256) >> 3, wcc1 = (t + 256) & 7;
  const unsigned short* whp0 = Wh + (gy * 64 + wr0) * EMB + wcc0 * 8;
  const unsigned short* whp1 = Wh + (gy * 64 + wr1) * EMB + wcc1 * 8;
  const unsigned short* wlp0 = Wl + (gy * 64 + wr0) * EMB + wcc0 * 8;
  const unsigned short* wlp1 = Wl + (gy * 64 + wr1) * EMB + wcc1 * 8;

  // prefetch stage 0
  float4 px0 = *(const float4*)(xp + 0);
  float4 px1 = *(const float4*)(xp + 4);
  float4 px2 = *(const float4*)(xp + 8);
  float4 px3 = *(const float4*)(xp + 12);
  int4 pwh0 = *(const int4*)whp0, pwh1 = *(const int4*)whp1;
  int4 pwl0 = *(const int4*)wlp0, pwl1 = *(const int4*)wlp1;

  f32x4 acc[2][2];
  acc[0][0] = (f32x4){0.f,0.f,0.f,0.f}; acc[0][1] = (f32x4){0.f,0.f,0.f,0.f};
  acc[1][0] = (f32x4){0.f,0.f,0.f,0.f}; acc[1][1] = (f32x4){0.f,0.f,0.f,0.f};

  const int rA0 = 32 * (w & 1) + li,  rA1 = rA0 + 16;   // x rows
  const int rB0 = 32 * (w >> 1) + li, rB1 = rB0 + 16;   // W rows (heads)

  for (int s = 0; s < 16; ++s) {
    __syncthreads();
    {  // convert x fp32 -> bf16 hi/lo, 16B LDS writes
      unsigned hb[8], lb[8];
      float4 pf[4] = {px0, px1, px2, px3};
#pragma unroll
      for (int e = 0; e < 4; ++e) {
        unsigned short h0 = f2bf(pf[e].x), h1 = f2bf(pf[e].y);
        unsigned short h2 = f2bf(pf[e].z), h3 = f2bf(pf[e].w);
        unsigned short l0 = f2bf(pf[e].x - bf2f(h0));
        unsigned short l1 = f2bf(pf[e].y - bf2f(h1));
        unsigned short l2 = f2bf(pf[e].z - bf2f(h2));
        unsigned short l3 = f2bf(pf[e].w - bf2f(h3));
        hb[e*2]   = (unsigned)h0 | ((unsigned)h1 << 16);
        hb[e*2+1] = (unsigned)h2 | ((unsigned)h3 << 16);
        lb[e*2]   = (unsigned)l0 | ((unsigned)l1 << 16);
        lb[e*2+1] = (unsigned)l2 | ((unsigned)l3 << 16);
      }
      int4 A0; A0.x = hb[0]; A0.y = hb[1]; A0.z = hb[2]; A0.w = hb[3];
      int4 A1; A1.x = hb[4]; A1.y = hb[5]; A1.z = hb[6]; A1.w = hb[7];
      int4 B0; B0.x = lb[0]; B0.y = lb[1]; B0.z = lb[2]; B0.w = lb[3];
      int4 B1; B1.x = lb[4]; B1.y = lb[5]; B1.z = lb[6]; B1.w = lb[7];
      *(int4*)&XhS[swzi(xr, xc2)]     = A0;
      *(int4*)&XhS[swzi(xr, xc2 + 1)] = A1;
      *(int4*)&XlS[swzi(xr, xc2)]     = B0;
      *(int4*)&XlS[swzi(xr, xc2 + 1)] = B1;
      *(int4*)&WhS[swzi(wr0, wcc0)] = pwh0;
      *(int4*)&WhS[swzi(wr1, wcc1)] = pwh1;
      *(int4*)&WlS[swzi(wr0, wcc0)] = pwl0;
      *(int4*)&WlS[swzi(wr1, wcc1)] = pwl1;
    }
    __syncthreads();

    if (s < 15) {  // next stage's globals fly during compute
      const int ko = (s + 1) * 64;
      px0 = *(const float4*)(xp + ko + 0);
      px1 = *(const float4*)(xp + ko + 4);
      px2 = *(const float4*)(xp + ko + 8);
      px3 = *(const float4*)(xp + ko + 12);
      pwh0 = *(const int4*)(whp0 + ko); pwh1 = *(const int4*)(whp1 + ko);
      pwl0 = *(const int4*)(wlp0 + ko); pwl1 = *(const int4*)(wlp1 + ko);
    }

#pragma unroll
    for (int ks = 0; ks < 2; ++ks) {
      const int cc = ks * 4 + g;
      bf16x8 ah0 = *(const bf16x8*)&XhS[swzi(rA0, cc)];
      bf16x8 ah1 = *(const bf16x8*)&XhS[swzi(rA1, cc)];
      bf16x8 al0 = *(const bf16x8*)&XlS[swzi(rA0, cc)];
      bf16x8 al1 = *(const bf16x8*)&XlS[swzi(rA1, cc)];
      bf16x8 bh0 = *(const bf16x8*)&WhS[swzi(rB0, cc)];
      bf16x8 bh1 = *(const bf16x8*)&WhS[swzi(rB1, cc)];
      bf16x8 bl0 = *(const bf16x8*)&WlS[swzi(rB0, cc)];
      bf16x8 bl1 = *(const bf16x8*)&WlS[swzi(rB1, cc)];
      acc[0][0] = __builtin_amdgcn_mfma_f32_16x16x32_bf16(ah0, bh0, acc[0][0], 0,0,0);
      acc[0][0] = __builtin_amdgcn_mfma_f32_16x16x32_bf16(ah0, bl0, acc[0][0], 0,0,0);
      acc[0][0] = __builtin_amdgcn_mfma_f32_16x16x32_bf16(al0, bh0, acc[0][0], 0,0,0);
      acc[0][1] = __builtin_amdgcn_mfma_f32_16x16x32_bf16(ah0, bh1, acc[0][1], 0,0,0);
      acc[0][1] = __builtin_amdgcn_mfma_f32_16x16x32_bf16(ah0, bl1, acc[0][1], 0,0,0);
      acc[0][1] = __builtin_amdgcn_mfma_f32_16x16x32_bf16(al0, bh1, acc[0][1], 0,0,0);
      acc[1][0] = __builtin_amdgcn_mfma_f32_16x16x32_bf16(ah1, bh0, acc[1][0], 0,0,0);
      acc[1][0] = __builtin_amdgcn_mfma_f32_16x16x32_bf16(ah1, bl0, acc[1][0], 0,0,0);
      acc[1][0] = __builtin_amdgcn_mfma_f32_16x16x32_bf16(al1, bh0, acc[1][0], 0,0,0);
      acc[1][1] = __builtin_amdgcn_mfma_f32_16x16x32_bf16(ah1, bh1, acc[1][1], 0,0,0);
      acc[1][1] = __builtin_amdgcn_mfma_f32_16x16x32_bf16(ah1, bl1, acc[1][1], 0,0,0);
      acc[1][1] = __builtin_amdgcn_mfma_f32_16x16x32_bf16(al1, bh1, acc[1][1], 0,0,0);
    }
  }

  // Epilogue. D[m = 16*mt+4g+r][n = 16*nt+li], mt/nt in wave's quadrant.
  if (gy != 2) {
    unsigned short* __restrict__ oh = (gy == 0) ? qh : kh;
    unsigned short* __restrict__ ol = (gy == 0) ? ql : kl;
#pragma unroll
    for (int i = 0; i < 2; ++i)
#pragma unroll
      for (int j = 0; j < 2; ++j) {
        const int hcol = 32 * (w >> 1) + 16 * j + li;
#pragma unroll
        for (int r = 0; r < 4; ++r) {
          const int mrow = 32 * (w & 1) + 16 * i + 4 * g + r;
          const float vv = acc[i][j][r];
          const unsigned short hbits = f2bf(vv);
          const unsigned short lbits = f2bf(vv - bf2f(hbits));
          const int off = (b * SEQ + n0 + mrow) * HS + hcol;
          oh[off] = hbits;
          ol[off] = lbits;
        }
      }
  } else {
#pragma unroll
    for (int i = 0; i < 2; ++i)
#pragma unroll
      for (int j = 0; j < 2; ++j) {
        const int hcol = 32 * (w >> 1) + 16 * j + li;
#pragma unroll
        for (int r = 0; r < 4; ++r) {
          const int mrow = 32 * (w & 1) + 16 * i + 4 * g + r;
          vt[(b * HS + hcol) * SEQ + n0 + mrow] = f2bf(acc[i][j][r]);
        }
      }
  }
}

// ---------------------------------------------------------------------------
// Flash attention, MFMA, O^T orientation, key-split wave pairs.
// Grid (128, NB): 32 q-rows per block, 256 thr = 4 waves.
// Wave w: qg = w&1 (16 q-cols: q0+16qg+li), s = w>>1 (key stream).
// Stream s processes key tiles 2i+s, i=0..31; merged at the end via LDS.
// S^T = K.Q^T (split-bf16, q = lane&15); softmax per-lane (no broadcasts);
// O^T = V^T.P (q = lane&15 -> alpha/l rescale per-lane, zero shuffles).
// ---------------------------------------------------------------------------
__global__ __launch_bounds__(256) void attn_mfma(
    const unsigned short* __restrict__ qh, const unsigned short* __restrict__ ql,
    const unsigned short* __restrict__ kh, const unsigned short* __restrict__ kl,
    const unsigned short* __restrict__ vt, float* __restrict__ out) {
  __shared__ __align__(16) unsigned short KhS[2][4096];
  __shared__ __align__(16) unsigned short KlS[2][4096];
  __shared__ __align__(16) unsigned short VtS[2][4096];
  __shared__ __align__(16) unsigned short PtS[2][2048];
  __shared__ float OTm[64 * 32];
  __shared__ float MM[2][32], LL[2][32];

  const int t  = threadIdx.x;
  const int l  = t & 63;
  const int li = l & 15;
  const int g  = l >> 4;
  const int w  = t >> 6;
  const int qg = w & 1;
  const int s  = w >> 1;          // == t>>7: staging stream matches wave pair
  const int b  = blockIdx.y;
  const int q0 = blockIdx.x * 32;

  // Persistent Q fragments (B-operand: B[k=h][n=q], n=li).
  bf16x8 qfh[2], qfl[2];
  {
    const unsigned short* qrh = qh + (b * SEQ + q0 + 16 * qg + li) * HS;
    const unsigned short* qrl = ql + (b * SEQ + q0 + 16 * qg + li) * HS;
    qfh[0] = *(const bf16x8*)&qrh[g * 8];
    qfh[1] = *(const bf16x8*)&qrh[32 + g * 8];
    qfl[0] = *(const bf16x8*)&qrl[g * 8];
    qfl[1] = *(const bf16x8*)&qrl[32 + g * 8];
  }

  // Staging: 128 threads per stream, 4 chunks per array each.
  int srow[4], sccs[4], sdst[4];
#pragma unroll
  for (int j = 0; j < 4; ++j) {
    const int c = (t & 127) + 128 * j;
    srow[j] = c >> 3; sccs[j] = c & 7;
    sdst[j] = swzi(srow[j], sccs[j]);
  }
  const unsigned short* khB = kh + b * SEQ * HS;
  const unsigned short* klB = kl + b * SEQ * HS;
  const unsigned short* vtB = vt + b * HS * SEQ;

  int4 pk[4], pl[4], pv[4];
  {
    const int kt0 = s * 64;
#pragma unroll
    for (int j = 0; j < 4; ++j) {
      pk[j] = *(const int4*)&khB[(kt0 + srow[j]) * HS + sccs[j] * 8];
      pl[j] = *(const int4*)&klB[(kt0 + srow[j]) * HS + sccs[j] * 8];
      pv[j] = *(const int4*)&vtB[srow[j] * SEQ + kt0 + sccs[j] * 8];
    }
  }

  float m = -1e30f, lsum = 0.f;
  f32x4 O[4];
  O[0] = (f32x4){0.f,0.f,0.f,0.f}; O[1] = (f32x4){0.f,0.f,0.f,0.f};
  O[2] = (f32x4){0.f,0.f,0.f,0.f}; O[3] = (f32x4){0.f,0.f,0.f,0.f};

  const int prow = 16 * qg + li;  // P^T row this lane owns (wave-local)

  for (int it = 0; it < 32; ++it) {
    __syncthreads();
#pragma unroll
    for (int j = 0; j < 4; ++j) {
      *(int4*)&KhS[s][sdst[j]] = pk[j];
      *(int4*)&KlS[s][sdst[j]] = pl[j];
      *(int4*)&VtS[s][sdst[j]] = pv[j];
    }
    __syncthreads();

    {  // prefetch next key tile of this stream
      const int kt0 = (2 * ((it + 1) & 31) + s) * 64;
#pragma unroll
      for (int j = 0; j < 4; ++j) {
        pk[j] = *(const int4*)&khB[(kt0 + srow[j]) * HS + sccs[j] * 8];
        pl[j] = *(const int4*)&klB[(kt0 + srow[j]) * HS + sccs[j] * 8];
        pv[j] = *(const int4*)&vtB[srow[j] * SEQ + kt0 + sccs[j] * 8];
      }
    }

    // S^T[key][q]: lane holds keys 16tt+4g+r, q = 16qg+li.
    f32x4 S[4];
    S[0] = (f32x4){0.f,0.f,0.f,0.f}; S[1] = (f32x4){0.f,0.f,0.f,0.f};
    S[2] = (f32x4){0.f,0.f,0.f,0.f}; S[3] = (f32x4){0.f,0.f,0.f,0.f};
#pragma unroll
    for (int khf = 0; khf < 2; ++khf) {
      const int cc = khf * 4 + g;
#pragma unroll
      for (int tt = 0; tt < 4; ++tt) {
        bf16x8 akh = *(const bf16x8*)&KhS[s][swzi(16 * tt + li, cc)];
        bf16x8 akl = *(const bf16x8*)&KlS[s][swzi(16 * tt + li, cc)];
        S[tt] = __builtin_amdgcn_mfma_f32_16x16x32_bf16(akh, qfh[khf], S[tt], 0,0,0);
        S[tt] = __builtin_amdgcn_mfma_f32_16x16x32_bf16(akh, qfl[khf], S[tt], 0,0,0);
        S[tt] = __builtin_amdgcn_mfma_f32_16x16x32_bf16(akl, qfh[khf], S[tt], 0,0,0);
      }
    }

    // Online softmax, log2 domain, per-lane q. Only 4 xor-shuffles.
    float m0 = fmaxf(fmaxf(S[0][0], S[0][1]), fmaxf(S[0][2], S[0][3]));
    float m1 = fmaxf(fmaxf(S[1][0], S[1][1]), fmaxf(S[1][2], S[1][3]));
    float m2 = fmaxf(fmaxf(S[2][0], S[2][1]), fmaxf(S[2][2], S[2][3]));
    float m3 = fmaxf(fmaxf(S[3][0], S[3][1]), fmaxf(S[3][2], S[3][3]));
    float mloc = fmaxf(fmaxf(m0, m1), fmaxf(m2, m3));
    mloc = fmaxf(mloc, __shfl_xor(mloc, 16));
    mloc = fmaxf(mloc, __shfl_xor(mloc, 32));
    const float mnew  = fmaxf(m, mloc);
    const float alpha = exp2f(m - mnew);
    float ls = 0.f;
#pragma unroll
    for (int tt = 0; tt < 4; ++tt)
#pragma unroll
      for (int rr = 0; rr < 4; ++rr) {
        const float p = exp2f(S[tt][rr] - mnew);
        S[tt][rr] = p;
        ls += p;
      }
    ls += __shfl_xor(ls, 16);
    ls += __shfl_xor(ls, 32);
    lsum = lsum * alpha + ls;
    m = mnew;

    // P^T -> LDS bf16, wave-local rows (no barrier; DS pipe in-order).
#pragma unroll
    for (int tt = 0; tt < 4; ++tt) {
      const int key = 16 * tt + 4 * g;
      const int idx = prow * 64 + (((key >> 3) ^ (prow & 7)) << 3) + (key & 7);
      const unsigned int p01 =
          (unsigned int)f2bf(S[tt][0]) | ((unsigned int)f2bf(S[tt][1]) << 16);
      const unsigned int p23 =
          (unsigned int)f2bf(S[tt][2]) | ((unsigned int)f2bf(S[tt][3]) << 16);
      *(unsigned int*)&PtS[s][idx]     = p01;
      *(unsigned int*)&PtS[s][idx + 2] = p23;
    }

    // Rescale O^T by per-lane alpha (no shuffles: O col = q = li).
#pragma unroll
    for (int ht = 0; ht < 4; ++ht) {
      O[ht][0] *= alpha; O[ht][1] *= alpha;
      O[ht][2] *= alpha; O[ht][3] *= alpha;
    }

    asm volatile("" ::: "memory");

    // O^T += V^T . P : A = V^T rows h, B = P rows q (operand roles swapped).
#pragma unroll
    for (int khf = 0; khf < 2; ++khf) {
      const int cc = khf * 4 + g;
      bf16x8 pb = *(const bf16x8*)&PtS[s][swzi(prow, cc)];
#pragma unroll
      for (int ht = 0; ht < 4; ++ht) {
        bf16x8 va = *(const bf16x8*)&VtS[s][swzi(16 * ht + li, cc)];
        O[ht] = __builtin_amdgcn_mfma_f32_16x16x32_bf16(va, pb, O[ht], 0,0,0);
      }
    }
  }

  // ---- merge the two key streams ----
  if (g == 0) { MM[s][16 * qg + li] = m; LL[s][16 * qg + li] = lsum; }
  __syncthreads();
  const float mo  = MM[s ^ 1][16 * qg + li];
  const float lo2 = LL[s ^ 1][16 * qg + li];
  const float mF = fmaxf(m, mo);
  const float f  = exp2f(m - mF);
  const float lF = lsum * f + lo2 * exp2f(mo - mF);
#pragma unroll
  for (int ht = 0; ht < 4; ++ht) {
    O[ht][0] *= f; O[ht][1] *= f; O[ht][2] *= f; O[ht][3] *= f;
  }
  if (s == 0) {
#pragma unroll
    for (int ht = 0; ht < 4; ++ht)
#pragma unroll
      for (int r = 0; r < 4; ++r)
        OTm[(16 * ht + 4 * g + r) * 32 + 16 * qg + li] = O[ht][r];
  }
  __syncthreads();
  if (s == 1) {
    const float inv = 1.f / lF;
    const int qrow = b * SEQ + q0 + 16 * qg + li;
#pragma unroll
    for (int ht = 0; ht < 4; ++ht) {
      float4 o4;
      o4.x = (O[ht][0] + OTm[(16 * ht + 4 * g + 0) * 32 + 16 * qg + li]) * inv;
      o4.y = (O[ht][1] + OTm[(16 * ht + 4 * g + 1) * 32 + 16 * qg + li]) * inv;
      o4.z = (O[ht][2] + OTm[(16 * ht + 4 * g + 2) * 32 + 16 * qg + li]) * inv;
      o4.w = (O[ht][3] + OTm[(16 * ht + 4 * g + 3) * 32 + 16 * qg + li]) * inv;
      *(float4*)&out[qrow * HS + 16 * ht + 4 * g] = o4;
    }
  }
}

// ---------------------------------------------------------------------------
extern "C" void kernel_launch(void* const* d_in, const int* in_sizes, int n_in,
                              void* d_out, int out_size, void* d_ws,
                              size_t ws_size, hipStream_t stream) {
  const float* x  = (const float*)d_in[0];
  const float* Wk = (const float*)d_in[1];
  const float* Wq = (const float*)d_in[2];
  const float* Wv = (const float*)d_in[3];
  float* out = (float*)d_out;

  unsigned short* us = (unsigned short*)d_ws;
  unsigned short* qh = us + 0 * (1 << 20);   // [B][N][H] bf16 hi
  unsigned short* ql = us + 1 * (1 << 20);   // [B][N][H] bf16 lo
  unsigned short* kh = us + 2 * (1 << 20);
  unsigned short* kl = us + 3 * (1 << 20);
  unsigned short* vt = us + 4 * (1 << 20);   // [B][H][N] bf16
  unsigned short* Wh = us + 5 * (1 << 20);   // [192][1024] bf16 hi
  unsigned short* Wl = Wh + 192 * 1024;      // [192][1024] bf16 lo

  wprep<<<192, 256, 0, stream>>>(Wk, Wq, Wv, Wh, Wl);
  qkv_mfma<<<dim3(256, 3), 256, 0, stream>>>(x, Wh, Wl, qh, ql, kh, kl, vt);
  attn_mfma<<<dim3(128, NB), 256, 0, stream>>>(qh, ql, kh, kl, vt, out);
}

// Round 5
// 210.777 us; speedup vs baseline: 1.6178x; 1.6178x over previous
//
#include <hip/hip_runtime.h>

#define NB   4
#define SEQ  4096
#define EMB  1024
#define HS   64

typedef __attribute__((ext_vector_type(8))) short bf16x8;   // 8 bf16 = 4 VGPRs
typedef __attribute__((ext_vector_type(4))) float f32x4;    // MFMA C/D

__device__ inline unsigned short f2bf(float f) {  // fp32 -> bf16 RNE
  unsigned int u = __float_as_uint(f);
  u += 0x7fffu + ((u >> 16) & 1u);
  return (unsigned short)(u >> 16);
}
__device__ inline float bf2f(unsigned short h) {
  return __uint_as_float(((unsigned int)h) << 16);
}
// ushort index of 16B chunk (row, c) in a 64x64 bf16 LDS tile, XOR-swizzled
// so b128 frag reads (16 lanes = 16 consecutive rows, same c) are conflict-free.
__device__ inline int swzi(int row, int c) {
  return row * 64 + ((c ^ (row & 7)) << 3);
}
// Async global->LDS 16B. LDS dest must be wave-uniform; lane i lands at +16*i.
// Swizzle is realized on the GLOBAL side: lane l fetches chunk (l&7)^(l>>3) of
// row (l>>3), which is exactly what swzi() puts at LDS slot l of a 1KB segment.
__device__ inline void gld16(const unsigned short* g, unsigned short* l) {
  __builtin_amdgcn_global_load_lds(
      (const __attribute__((address_space(1))) void*)g,
      (__attribute__((address_space(3))) void*)l, 16, 0, 0);
}

// ---------------------------------------------------------------------------
// x prep: split x fp32 -> bf16 hi/lo once (memory-bound). 8 floats/thread.
// ---------------------------------------------------------------------------
__global__ __launch_bounds__(256) void xprep(
    const float* __restrict__ x, unsigned short* __restrict__ xh,
    unsigned short* __restrict__ xl) {
  const int i = blockIdx.x * 256 + threadIdx.x;  // 8-float group, 2M total
  float4 a = ((const float4*)x)[2 * i];
  float4 c = ((const float4*)x)[2 * i + 1];
  float f[8] = {a.x, a.y, a.z, a.w, c.x, c.y, c.z, c.w};
  unsigned hp[4], lp[4];
#pragma unroll
  for (int e = 0; e < 4; ++e) {
    unsigned short h0 = f2bf(f[2 * e]), h1 = f2bf(f[2 * e + 1]);
    unsigned short l0 = f2bf(f[2 * e] - bf2f(h0));
    unsigned short l1 = f2bf(f[2 * e + 1] - bf2f(h1));
    hp[e] = (unsigned)h0 | ((unsigned)h1 << 16);
    lp[e] = (unsigned)l0 | ((unsigned)l1 << 16);
  }
  int4 hv; hv.x = hp[0]; hv.y = hp[1]; hv.z = hp[2]; hv.w = hp[3];
  int4 lv; lv.x = lp[0]; lv.y = lp[1]; lv.z = lp[2]; lv.w = lp[3];
  *(int4*)&xh[i * 8] = hv;
  *(int4*)&xl[i * 8] = lv;
}

// ---------------------------------------------------------------------------
// W prep: split Wq*scale*log2e | Wk | Wv into bf16 hi/lo [192][1024].
// ---------------------------------------------------------------------------
__global__ __launch_bounds__(256) void wprep(
    const float* __restrict__ Wk, const float* __restrict__ Wq,
    const float* __restrict__ Wv,
    unsigned short* __restrict__ Wh, unsigned short* __restrict__ Wl) {
  int i = blockIdx.x * 256 + threadIdx.x;  // float4 id, 192*1024/4 = 49152
  int e = i >> 8;
  int c = i & 255;
  float4 v;
  float sc = 1.0f;
  if (e < 64)       { v = ((const float4*)Wq)[e * 256 + c];
                      sc = 0.18033688011112042f; }  // (1/sqrt(64))*log2(e)
  else if (e < 128)   v = ((const float4*)Wk)[(e - 64) * 256 + c];
  else                v = ((const float4*)Wv)[(e - 128) * 256 + c];
  v.x *= sc; v.y *= sc; v.z *= sc; v.w *= sc;
  ushort4 hv, lv;
  hv.x = f2bf(v.x); lv.x = f2bf(v.x - bf2f(hv.x));
  hv.y = f2bf(v.y); lv.y = f2bf(v.y - bf2f(hv.y));
  hv.z = f2bf(v.z); lv.z = f2bf(v.z - bf2f(hv.z));
  hv.w = f2bf(v.w); lv.w = f2bf(v.w - bf2f(hv.w));
  *(ushort4*)&Wh[i * 4] = hv;
  *(ushort4*)&Wl[i * 4] = lv;
}

// ---------------------------------------------------------------------------
// Shared MFMA body + epilogue for the QKV GEMM (both staging variants).
// Wave owns 32x32 quadrant; acc += Ah.Bh + Ah.Bl + Al.Bh.
// ---------------------------------------------------------------------------
#define QKV_COMPUTE(XhS, XlS, WhS, WlS)                                        \
  _Pragma("unroll")                                                            \
  for (int ks = 0; ks < 2; ++ks) {                                             \
    const int cc = ks * 4 + g;                                                 \
    bf16x8 ah0 = *(const bf16x8*)&XhS[swzi(rA0, cc)];                          \
    bf16x8 ah1 = *(const bf16x8*)&XhS[swzi(rA1, cc)];                          \
    bf16x8 al0 = *(const bf16x8*)&XlS[swzi(rA0, cc)];                          \
    bf16x8 al1 = *(const bf16x8*)&XlS[swzi(rA1, cc)];                          \
    bf16x8 bh0 = *(const bf16x8*)&WhS[swzi(rB0, cc)];                          \
    bf16x8 bh1 = *(const bf16x8*)&WhS[swzi(rB1, cc)];                          \
    bf16x8 bl0 = *(const bf16x8*)&WlS[swzi(rB0, cc)];                          \
    bf16x8 bl1 = *(const bf16x8*)&WlS[swzi(rB1, cc)];                          \
    acc[0][0] = __builtin_amdgcn_mfma_f32_16x16x32_bf16(ah0, bh0, acc[0][0], 0,0,0); \
    acc[0][0] = __builtin_amdgcn_mfma_f32_16x16x32_bf16(ah0, bl0, acc[0][0], 0,0,0); \
    acc[0][0] = __builtin_amdgcn_mfma_f32_16x16x32_bf16(al0, bh0, acc[0][0], 0,0,0); \
    acc[0][1] = __builtin_amdgcn_mfma_f32_16x16x32_bf16(ah0, bh1, acc[0][1], 0,0,0); \
    acc[0][1] = __builtin_amdgcn_mfma_f32_16x16x32_bf16(ah0, bl1, acc[0][1], 0,0,0); \
    acc[0][1] = __builtin_amdgcn_mfma_f32_16x16x32_bf16(al0, bh1, acc[0][1], 0,0,0); \
    acc[1][0] = __builtin_amdgcn_mfma_f32_16x16x32_bf16(ah1, bh0, acc[1][0], 0,0,0); \
    acc[1][0] = __builtin_amdgcn_mfma_f32_16x16x32_bf16(ah1, bl0, acc[1][0], 0,0,0); \
    acc[1][0] = __builtin_amdgcn_mfma_f32_16x16x32_bf16(al1, bh0, acc[1][0], 0,0,0); \
    acc[1][1] = __builtin_amdgcn_mfma_f32_16x16x32_bf16(ah1, bh1, acc[1][1], 0,0,0); \
    acc[1][1] = __builtin_amdgcn_mfma_f32_16x16x32_bf16(ah1, bl1, acc[1][1], 0,0,0); \
    acc[1][1] = __builtin_amdgcn_mfma_f32_16x16x32_bf16(al1, bh1, acc[1][1], 0,0,0); \
  }

#define QKV_EPILOGUE                                                           \
  if (gy != 2) {                                                               \
    unsigned short* __restrict__ oh = (gy == 0) ? qh : kh;                     \
    unsigned short* __restrict__ ol = (gy == 0) ? ql : kl;                     \
    _Pragma("unroll")                                                          \
    for (int i = 0; i < 2; ++i)                                                \
      _Pragma("unroll")                                                        \
      for (int j = 0; j < 2; ++j) {                                            \
        const int hcol = 32 * (w >> 1) + 16 * j + li;                          \
        _Pragma("unroll")                                                      \
        for (int r = 0; r < 4; ++r) {                                          \
          const int mrow = 32 * (w & 1) + 16 * i + 4 * g + r;                  \
          const float vv = acc[i][j][r];                                       \
          const unsigned short hbits = f2bf(vv);                               \
          const unsigned short lbits = f2bf(vv - bf2f(hbits));                 \
          const int off = (b * SEQ + n0 + mrow) * HS + hcol;                   \
          oh[off] = hbits;                                                     \
          ol[off] = lbits;                                                     \
        }                                                                      \
      }                                                                        \
  } else {                                                                     \
    _Pragma("unroll")                                                          \
    for (int i = 0; i < 2; ++i)                                                \
      _Pragma("unroll")                                                        \
      for (int j = 0; j < 2; ++j) {                                            \
        const int hcol = 32 * (w >> 1) + 16 * j + li;                          \
        _Pragma("unroll")                                                      \
        for (int r = 0; r < 4; ++r) {                                          \
          const int mrow = 32 * (w & 1) + 16 * i + 4 * g + r;                  \
          vt[(b * HS + hcol) * SEQ + n0 + mrow] = f2bf(acc[i][j][r]);          \
        }                                                                      \
      }                                                                        \
  }

// ---------------------------------------------------------------------------
// QKV GEMM, global_load_lds staging of pre-split xh/xl (primary path).
// Grid (256, 3), 256 thr = 4 waves, BK=64, 16 stages.
// ---------------------------------------------------------------------------
__global__ __launch_bounds__(256) void qkv_lds(
    const unsigned short* __restrict__ xh, const unsigned short* __restrict__ xl,
    const unsigned short* __restrict__ Wh, const unsigned short* __restrict__ Wl,
    unsigned short* __restrict__ qh, unsigned short* __restrict__ ql,
    unsigned short* __restrict__ kh, unsigned short* __restrict__ kl,
    unsigned short* __restrict__ vt) {
  __shared__ __align__(16) unsigned short XhS[4096];
  __shared__ __align__(16) unsigned short XlS[4096];
  __shared__ __align__(16) unsigned short WhS[4096];
  __shared__ __align__(16) unsigned short WlS[4096];

  const int t  = threadIdx.x;
  const int l  = t & 63;
  const int li = l & 15;
  const int g  = l >> 4;
  const int w  = t >> 6;
  const int m0 = blockIdx.x * 64;
  const int b  = m0 >> 12;
  const int n0 = m0 & 4095;
  const int gy = blockIdx.y;  // 0=q, 1=k, 2=v

  // per-lane inverse-swizzle global map
  const int rl = l >> 3;
  const int cl = (l & 7) ^ rl;
  const unsigned short* xhL = xh + (m0 + rl) * EMB + cl * 8;
  const unsigned short* xlL = xl + (m0 + rl) * EMB + cl * 8;
  const unsigned short* whL = Wh + (gy * 64 + rl) * EMB + cl * 8;
  const unsigned short* wlL = Wl + (gy * 64 + rl) * EMB + cl * 8;
  const int segb = __builtin_amdgcn_readfirstlane(w) * 2;

  f32x4 acc[2][2];
  acc[0][0] = (f32x4){0.f,0.f,0.f,0.f}; acc[0][1] = (f32x4){0.f,0.f,0.f,0.f};
  acc[1][0] = (f32x4){0.f,0.f,0.f,0.f}; acc[1][1] = (f32x4){0.f,0.f,0.f,0.f};

  const int rA0 = 32 * (w & 1) + li,  rA1 = rA0 + 16;   // x rows
  const int rB0 = 32 * (w >> 1) + li, rB1 = rB0 + 16;   // W rows (heads)

  for (int st = 0; st < 16; ++st) {
    const int ko = st * 64;
    __syncthreads();  // prev tile consumed by all waves
#pragma unroll
    for (int i = 0; i < 2; ++i) {
      const int seg = segb + i;
      gld16(xhL + seg * 8 * EMB + ko, &XhS[seg * 512]);
      gld16(xlL + seg * 8 * EMB + ko, &XlS[seg * 512]);
      gld16(whL + seg * 8 * EMB + ko, &WhS[seg * 512]);
      gld16(wlL + seg * 8 * EMB + ko, &WlS[seg * 512]);
    }
    __syncthreads();  // drains vmcnt -> tile ready
    QKV_COMPUTE(XhS, XlS, WhS, WlS)
  }
  QKV_EPILOGUE
}

// ---------------------------------------------------------------------------
// QKV GEMM fallback (round-4 proven path): in-kernel x conversion, register
// prefetch. Used only if ws_size can't hold xh/xl.
// ---------------------------------------------------------------------------
__global__ __launch_bounds__(256) void qkv_conv(
    const float* __restrict__ x,
    const unsigned short* __restrict__ Wh, const unsigned short* __restrict__ Wl,
    unsigned short* __restrict__ qh, unsigned short* __restrict__ ql,
    unsigned short* __restrict__ kh, unsigned short* __restrict__ kl,
    unsigned short* __restrict__ vt) {
  __shared__ __align__(16) unsigned short XhS[4096];
  __shared__ __align__(16) unsigned short XlS[4096];
  __shared__ __align__(16) unsigned short WhS[4096];
  __shared__ __align__(16) unsigned short WlS[4096];

  const int t  = threadIdx.x;
  const int l  = t & 63;
  const int li = l & 15;
  const int g  = l >> 4;
  const int w  = t >> 6;
  const int m0 = blockIdx.x * 64;
  const int b  = m0 >> 12;
  const int n0 = m0 & 4095;
  const int gy = blockIdx.y;

  const int xr  = t >> 2;
  const int xc2 = (t & 3) * 2;
  const float* xp = x + (m0 + xr) * EMB + (t & 3) * 16;
  const int wr0 = t >> 3,         wcc0 = t & 7;
  const int wr1 = (t + 256) >> 3, wcc1 = (t + 256) & 7;
  const unsigned short* whp0 = Wh + (gy * 64 + wr0) * EMB + wcc0 * 8;
  const unsigned short* whp1 = Wh + (gy * 64 + wr1) * EMB + wcc1 * 8;
  const unsigned short* wlp0 = Wl + (gy * 64 + wr0) * EMB + wcc0 * 8;
  const unsigned short* wlp1 = Wl + (gy * 64 + wr1) * EMB + wcc1 * 8;

  float4 px0 = *(const float4*)(xp + 0);
  float4 px1 = *(const float4*)(xp + 4);
  float4 px2 = *(const float4*)(xp + 8);
  float4 px3 = *(const float4*)(xp + 12);
  int4 pwh0 = *(const int4*)whp0, pwh1 = *(const int4*)whp1;
  int4 pwl0 = *(const int4*)wlp0, pwl1 = *(const int4*)wlp1;

  f32x4 acc[2][2];
  acc[0][0] = (f32x4){0.f,0.f,0.f,0.f}; acc[0][1] = (f32x4){0.f,0.f,0.f,0.f};
  acc[1][0] = (f32x4){0.f,0.f,0.f,0.f}; acc[1][1] = (f32x4){0.f,0.f,0.f,0.f};

  const int rA0 = 32 * (w & 1) + li,  rA1 = rA0 + 16;
  const int rB0 = 32 * (w >> 1) + li, rB1 = rB0 + 16;

  for (int st = 0; st < 16; ++st) {
    __syncthreads();
    {
      unsigned hb[8], lb[8];
      float4 pf[4] = {px0, px1, px2, px3};
#pragma unroll
      for (int e = 0; e < 4; ++e) {
        unsigned short h0 = f2bf(pf[e].x), h1 = f2bf(pf[e].y);
        unsigned short h2 = f2bf(pf[e].z), h3 = f2bf(pf[e].w);
        unsigned short l0 = f2bf(pf[e].x - bf2f(h0));
        unsigned short l1 = f2bf(pf[e].y - bf2f(h1));
        unsigned short l2 = f2bf(pf[e].z - bf2f(h2));
        unsigned short l3 = f2bf(pf[e].w - bf2f(h3));
        hb[e*2]   = (unsigned)h0 | ((unsigned)h1 << 16);
        hb[e*2+1] = (unsigned)h2 | ((unsigned)h3 << 16);
        lb[e*2]   = (unsigned)l0 | ((unsigned)l1 << 16);
        lb[e*2+1] = (unsigned)l2 | ((unsigned)l3 << 16);
      }
      int4 A0; A0.x = hb[0]; A0.y = hb[1]; A0.z = hb[2]; A0.w = hb[3];
      int4 A1; A1.x = hb[4]; A1.y = hb[5]; A1.z = hb[6]; A1.w = hb[7];
      int4 B0; B0.x = lb[0]; B0.y = lb[1]; B0.z = lb[2]; B0.w = lb[3];
      int4 B1; B1.x = lb[4]; B1.y = lb[5]; B1.z = lb[6]; B1.w = lb[7];
      *(int4*)&XhS[swzi(xr, xc2)]     = A0;
      *(int4*)&XhS[swzi(xr, xc2 + 1)] = A1;
      *(int4*)&XlS[swzi(xr, xc2)]     = B0;
      *(int4*)&XlS[swzi(xr, xc2 + 1)] = B1;
      *(int4*)&WhS[swzi(wr0, wcc0)] = pwh0;
      *(int4*)&WhS[swzi(wr1, wcc1)] = pwh1;
      *(int4*)&WlS[swzi(wr0, wcc0)] = pwl0;
      *(int4*)&WlS[swzi(wr1, wcc1)] = pwl1;
    }
    __syncthreads();

    if (st < 15) {
      const int ko = (st + 1) * 64;
      px0 = *(const float4*)(xp + ko + 0);
      px1 = *(const float4*)(xp + ko + 4);
      px2 = *(const float4*)(xp + ko + 8);
      px3 = *(const float4*)(xp + ko + 12);
      pwh0 = *(const int4*)(whp0 + ko); pwh1 = *(const int4*)(whp1 + ko);
      pwl0 = *(const int4*)(wlp0 + ko); pwl1 = *(const int4*)(wlp1 + ko);
    }
    QKV_COMPUTE(XhS, XlS, WhS, WlS)
  }
  QKV_EPILOGUE
}

// ---------------------------------------------------------------------------
// Flash attention, MFMA, O^T orientation, key-split wave pairs,
// global_load_lds staging (no register prefetch -> no spill).
// Grid (128, NB): 32 q-rows/block, 4 waves. Wave w: qg=w&1, stream s=w>>1.
// ---------------------------------------------------------------------------
__global__ __launch_bounds__(256) void attn_mfma(
    const unsigned short* __restrict__ qh, const unsigned short* __restrict__ ql,
    const unsigned short* __restrict__ kh, const unsigned short* __restrict__ kl,
    const unsigned short* __restrict__ vt, float* __restrict__ out) {
  __shared__ __align__(16) unsigned short KhS[2][4096];
  __shared__ __align__(16) unsigned short KlS[2][4096];
  __shared__ __align__(16) unsigned short VtS[2][4096];
  __shared__ __align__(16) unsigned short PtS[2][2048];
  __shared__ float OTm[64 * 32];
  __shared__ float MM[2][32], LL[2][32];

  const int t  = threadIdx.x;
  const int l  = t & 63;
  const int li = l & 15;
  const int g  = l >> 4;
  const int w  = t >> 6;
  const int qg = w & 1;
  const int s  = w >> 1;          // key stream
  const int b  = blockIdx.y;
  const int q0 = blockIdx.x * 32;

  // Persistent Q fragments (B-operand: B[k=h][n=q], n=li).
  bf16x8 qfh[2], qfl[2];
  {
    const unsigned short* qrh = qh + (b * SEQ + q0 + 16 * qg + li) * HS;
    const unsigned short* qrl = ql + (b * SEQ + q0 + 16 * qg + li) * HS;
    qfh[0] = *(const bf16x8*)&qrh[g * 8];
    qfh[1] = *(const bf16x8*)&qrh[32 + g * 8];
    qfl[0] = *(const bf16x8*)&qrl[g * 8];
    qfl[1] = *(const bf16x8*)&qrl[32 + g * 8];
  }

  // global_load_lds staging: per-lane inverse-swizzle global map.
  const int rl = l >> 3;
  const int cl = (l & 7) ^ rl;
  const unsigned short* khL = kh + (b * SEQ + rl) * HS + cl * 8;
  const unsigned short* klL = kl + (b * SEQ + rl) * HS + cl * 8;
  const unsigned short* vtL = vt + (b * HS + rl) * SEQ + cl * 8;
  // wave-within-stream picks 4 of the 8 1KB segments
  const int segb = __builtin_amdgcn_readfirstlane((t >> 6) & 1) * 4;

  float m = -1e30f, lsum = 0.f;
  f32x4 O[4];
  O[0] = (f32x4){0.f,0.f,0.f,0.f}; O[1] = (f32x4){0.f,0.f,0.f,0.f};
  O[2] = (f32x4){0.f,0.f,0.f,0.f}; O[3] = (f32x4){0.f,0.f,0.f,0.f};

  const int prow = 16 * qg + li;  // P^T row this lane owns (wave-local)

  for (int it = 0; it < 32; ++it) {
    const int kt0 = (2 * it + s) * 64;
    __syncthreads();  // prev tile consumed
#pragma unroll
    for (int i = 0; i < 4; ++i) {
      const int seg = segb + i;
      gld16(khL + (kt0 + seg * 8) * HS, &KhS[s][seg * 512]);
      gld16(klL + (kt0 + seg * 8) * HS, &KlS[s][seg * 512]);
      gld16(vtL + seg * 8 * SEQ + kt0,  &VtS[s][seg * 512]);
    }
    __syncthreads();  // drains vmcnt -> tile ready

    // S^T[key][q]: lane holds keys 16tt+4g+r, q = 16qg+li.
    f32x4 S[4];
    S[0] = (f32x4){0.f,0.f,0.f,0.f}; S[1] = (f32x4){0.f,0.f,0.f,0.f};
    S[2] = (f32x4){0.f,0.f,0.f,0.f}; S[3] = (f32x4){0.f,0.f,0.f,0.f};
#pragma unroll
    for (int khf = 0; khf < 2; ++khf) {
      const int cc = khf * 4 + g;
#pragma unroll
      for (int tt = 0; tt < 4; ++tt) {
        bf16x8 akh = *(const bf16x8*)&KhS[s][swzi(16 * tt + li, cc)];
        bf16x8 akl = *(const bf16x8*)&KlS[s][swzi(16 * tt + li, cc)];
        S[tt] = __builtin_amdgcn_mfma_f32_16x16x32_bf16(akh, qfh[khf], S[tt], 0,0,0);
        S[tt] = __builtin_amdgcn_mfma_f32_16x16x32_bf16(akh, qfl[khf], S[tt], 0,0,0);
        S[tt] = __builtin_amdgcn_mfma_f32_16x16x32_bf16(akl, qfh[khf], S[tt], 0,0,0);
      }
    }

    // Online softmax, log2 domain, per-lane q (only 4 xor-shuffles).
    float m0 = fmaxf(fmaxf(S[0][0], S[0][1]), fmaxf(S[0][2], S[0][3]));
    float m1 = fmaxf(fmaxf(S[1][0], S[1][1]), fmaxf(S[1][2], S[1][3]));
    float m2 = fmaxf(fmaxf(S[2][0], S[2][1]), fmaxf(S[2][2], S[2][3]));
    float m3 = fmaxf(fmaxf(S[3][0], S[3][1]), fmaxf(S[3][2], S[3][3]));
    float mloc = fmaxf(fmaxf(m0, m1), fmaxf(m2, m3));
    mloc = fmaxf(mloc, __shfl_xor(mloc, 16));
    mloc = fmaxf(mloc, __shfl_xor(mloc, 32));
    const float mnew  = fmaxf(m, mloc);
    const float alpha = exp2f(m - mnew);
    float ls = 0.f;
#pragma unroll
    for (int tt = 0; tt < 4; ++tt)
#pragma unroll
      for (int rr = 0; rr < 4; ++rr) {
        const float p = exp2f(S[tt][rr] - mnew);
        S[tt][rr] = p;
        ls += p;
      }
    ls += __shfl_xor(ls, 16);
    ls += __shfl_xor(ls, 32);
    lsum = lsum * alpha + ls;
    m = mnew;

    // P^T -> LDS bf16, wave-local rows (no barrier; DS pipe in-order per wave).
#pragma unroll
    for (int tt = 0; tt < 4; ++tt) {
      const int key = 16 * tt + 4 * g;
      const int idx = prow * 64 + (((key >> 3) ^ (prow & 7)) << 3) + (key & 7);
      const unsigned int p01 =
          (unsigned int)f2bf(S[tt][0]) | ((unsigned int)f2bf(S[tt][1]) << 16);
      const unsigned int p23 =
          (unsigned int)f2bf(S[tt][2]) | ((unsigned int)f2bf(S[tt][3]) << 16);
      *(unsigned int*)&PtS[s][idx]     = p01;
      *(unsigned int*)&PtS[s][idx + 2] = p23;
    }

    // Rescale O^T by per-lane alpha (O col = q = li; no shuffles).
#pragma unroll
    for (int ht = 0; ht < 4; ++ht) {
      O[ht][0] *= alpha; O[ht][1] *= alpha;
      O[ht][2] *= alpha; O[ht][3] *= alpha;
    }

    asm volatile("" ::: "memory");

    // O^T += V^T . P : A = V^T rows h, B = P rows q.
#pragma unroll
    for (int khf = 0; khf < 2; ++khf) {
      const int cc = khf * 4 + g;
      bf16x8 pb = *(const bf16x8*)&PtS[s][swzi(prow, cc)];
#pragma unroll
      for (int ht = 0; ht < 4; ++ht) {
        bf16x8 va = *(const bf16x8*)&VtS[s][swzi(16 * ht + li, cc)];
        O[ht] = __builtin_amdgcn_mfma_f32_16x16x32_bf16(va, pb, O[ht], 0,0,0);
      }
    }
  }

  // ---- merge the two key streams ----
  if (g == 0) { MM[s][16 * qg + li] = m; LL[s][16 * qg + li] = lsum; }
  __syncthreads();
  const float mo  = MM[s ^ 1][16 * qg + li];
  const float lo2 = LL[s ^ 1][16 * qg + li];
  const float mF = fmaxf(m, mo);
  const float f  = exp2f(m - mF);
  const float lF = lsum * f + lo2 * exp2f(mo - mF);
#pragma unroll
  for (int ht = 0; ht < 4; ++ht) {
    O[ht][0] *= f; O[ht][1] *= f; O[ht][2] *= f; O[ht][3] *= f;
  }
  if (s == 0) {
#pragma unroll
    for (int ht = 0; ht < 4; ++ht)
#pragma unroll
      for (int r = 0; r < 4; ++r)
        OTm[(16 * ht + 4 * g + r) * 32 + 16 * qg + li] = O[ht][r];
  }
  __syncthreads();
  if (s == 1) {
    const float inv = 1.f / lF;
    const int qrow = b * SEQ + q0 + 16 * qg + li;
#pragma unroll
    for (int ht = 0; ht < 4; ++ht) {
      float4 o4;
      o4.x = (O[ht][0] + OTm[(16 * ht + 4 * g + 0) * 32 + 16 * qg + li]) * inv;
      o4.y = (O[ht][1] + OTm[(16 * ht + 4 * g + 1) * 32 + 16 * qg + li]) * inv;
      o4.z = (O[ht][2] + OTm[(16 * ht + 4 * g + 2) * 32 + 16 * qg + li]) * inv;
      o4.w = (O[ht][3] + OTm[(16 * ht + 4 * g + 3) * 32 + 16 * qg + li]) * inv;
      *(float4*)&out[qrow * HS + 16 * ht + 4 * g] = o4;
    }
  }
}

// ---------------------------------------------------------------------------
extern "C" void kernel_launch(void* const* d_in, const int* in_sizes, int n_in,
                              void* d_out, int out_size, void* d_ws,
                              size_t ws_size, hipStream_t stream) {
  const float* x  = (const float*)d_in[0];
  const float* Wk = (const float*)d_in[1];
  const float* Wq = (const float*)d_in[2];
  const float* Wv = (const float*)d_in[3];
  float* out = (float*)d_out;

  unsigned short* us = (unsigned short*)d_ws;
  unsigned short* qh = us + 0 * (1 << 20);   // [B][N][H] bf16 hi
  unsigned short* ql = us + 1 * (1 << 20);   // [B][N][H] bf16 lo
  unsigned short* kh = us + 2 * (1 << 20);
  unsigned short* kl = us + 3 * (1 << 20);
  unsigned short* vt = us + 4 * (1 << 20);   // [B][H][N] bf16
  unsigned short* Wh = us + 5 * (1 << 20);   // [192][1024] bf16 hi
  unsigned short* Wl = Wh + 192 * 1024;      // [192][1024] bf16 lo
  unsigned short* xh = us + (size_t)(6) * (1 << 20);        // [B*N][E] bf16 hi
  unsigned short* xl = xh + (size_t)(16) * (1 << 20);       // [B*N][E] bf16 lo
  const size_t need = ((size_t)(6 + 32) << 20) * 2;         // 76 MB

  wprep<<<192, 256, 0, stream>>>(Wk, Wq, Wv, Wh, Wl);
  if (ws_size >= need) {
    xprep<<<8192, 256, 0, stream>>>(x, xh, xl);
    qkv_lds<<<dim3(256, 3), 256, 0, stream>>>(xh, xl, Wh, Wl,
                                              qh, ql, kh, kl, vt);
  } else {
    qkv_conv<<<dim3(256, 3), 256, 0, stream>>>(x, Wh, Wl,
                                               qh, ql, kh, kl, vt);
  }
  attn_mfma<<<dim3(128, NB), 256, 0, stream>>>(qh, ql, kh, kl, vt, out);
}